// Round 17
// baseline (306.745 us; speedup 1.0000x reference)
//
#include <hip/hip_runtime.h>
#include <stdint.h>

#define BB 32
#define SS 512
#define DD 640
#define HH 10
#define DKK 64
#define NTOK (BB*SS)   // 16384

using f32x4  = __attribute__((ext_vector_type(4))) float;
using bf16x8 = __attribute__((ext_vector_type(8))) __bf16;
using u32x4  = __attribute__((ext_vector_type(4))) unsigned int;
using u32x2  = __attribute__((ext_vector_type(2))) unsigned int;
using u16x4  = __attribute__((ext_vector_type(4))) unsigned short;
using i32x4  = __attribute__((ext_vector_type(4))) int;

__device__ inline unsigned short f2bf(float f){
  union { float f; unsigned int u; } v; v.f=f;
  unsigned int u=v.u;
  u += 0x7FFFu + ((u>>16)&1u);
  return (unsigned short)(u>>16);
}
__device__ inline float bf2f(unsigned short s){
  union { unsigned int u; float f; } v; v.u = ((unsigned int)s)<<16;
  return v.f;
}
__device__ inline unsigned int cvtpk_bf16(float lo, float hi){
  unsigned int r;
  asm volatile("v_cvt_pk_bf16_f32 %0, %1, %2" : "=v"(r) : "v"(lo), "v"(hi));
  return r;
}
__device__ inline void gload_lds16(const void* g, void* l){
  __builtin_amdgcn_global_load_lds(
      (const __attribute__((address_space(1))) unsigned int*)g,
      (__attribute__((address_space(3))) unsigned int*)l, 16, 0, 0);
}

// ---------------- merged prep: convert_qkv | convert_w | bias (R12) ----------
__global__ void prep_kernel(const float* __restrict__ q, const float* __restrict__ k,
                            const float* __restrict__ v,
                            const int* __restrict__ mask, const float* __restrict__ adj,
                            const int* __restrict__ layer,
                            const float* __restrict__ wq, const float* __restrict__ wk,
                            const float* __restrict__ wv, const float* __restrict__ rw,
                            unsigned short* __restrict__ xq, unsigned short* __restrict__ xk,
                            unsigned short* __restrict__ xv,
                            unsigned short* __restrict__ bwq, unsigned short* __restrict__ bwk,
                            unsigned short* __restrict__ bwv, unsigned short* __restrict__ brwt,
                            unsigned short* __restrict__ brwtf,
                            unsigned short* __restrict__ biasT)
{
  const int bid = blockIdx.x;
  const int tid = threadIdx.x;
  if (bid < 2048){
    int i = bid*256 + tid;
    const int n4 = (NTOK*DD)/4;
    for (; i < n4; i += 2048*256){
      f32x4 a = ((const f32x4*)q)[i];
      f32x4 b = ((const f32x4*)k)[i];
      f32x4 c = ((const f32x4*)v)[i];
      u16x4 ra, rb, rc;
      #pragma unroll
      for (int j=0;j<4;j++){ ra[j]=f2bf(a[j]); rb[j]=f2bf(b[j]); rc[j]=f2bf(c[j]); }
      ((u16x4*)xq)[i]=ra; ((u16x4*)xk)[i]=rb; ((u16x4*)xv)[i]=rc;
    }
  } else if (bid < 3648){
    const int i = (bid-2048)*256 + tid;
    if (i < DD*DD){
      bwq[i]=f2bf(wq[i]); bwk[i]=f2bf(wk[i]); bwv[i]=f2bf(wv[i]);
      unsigned short rv = f2bf(rw[i]);
      const int kk = i / DD;       // r*64 + ii
      const int o  = i % DD;
      brwt[o*DD + kk] = rv;        // final_gemm W operand (rows=o, cols=k)
      const int r  = kk >> 6, ii = kk & 63;
      const int ks = ii >> 5, rem = ii & 31, g = rem >> 3, j = rem & 7;
      const int oT = o >> 4, l15o = o & 15;
      brwtf[(size_t)((oT*10 + r)*2 + ks)*512 + (g*16 + l15o)*8 + j] = rv;
    }
  } else {
    float sc = 1.0f/(float)(layer[0]+1);
    int i = (bid-3648)*256 + tid;
    const int n4 = (BB*SS*SS)/4;
    for (; i < n4; i += 2048*256){
      i32x4 m = ((const i32x4*)mask)[i];
      f32x4 a = ((const f32x4*)adj)[i];
      u16x4 r;
      #pragma unroll
      for (int j=0;j<4;j++) r[j] = m[j] ? f2bf(a[j]*sc) : f2bf(-1e9f);
      const int e  = i*4;
      const int bb = e >> 18;
      const int qq = (e >> 9) & 511;
      const int kk = e & 511;
      const int idx = (((bb*32 + (qq>>4))*32 + (kk>>4))<<8) + ((qq&15)<<4) + (kk&15);
      *(u16x4*)(biasT + idx) = r;
    }
  }
}

// ---------------- GEMM body (128x128, BK=32, 256 thr, dbuf) ------------------
#define BM 128
#define BN 128
#define BK 32

template<bool SWAP, typename EPI>
__device__ inline void gemm_body(const unsigned short* __restrict__ A,
                                 const unsigned short* __restrict__ W,
                                 int m0, int n0, EPI&& epi)
{
  __shared__ unsigned short As[2][BM*BK];
  __shared__ unsigned short Ws[2][BN*BK];
  const int tid  = threadIdx.x;
  const int lane = tid & 63;
  const int wave = tid >> 6;
  const int wr   = (wave >> 1) * 64;
  const int wc   = (wave & 1) * 64;
  const int l15  = lane & 15;
  const int g    = lane >> 4;

  f32x4 acc[4][4];
  #pragma unroll
  for (int i=0;i<4;i++)
    #pragma unroll
    for (int j=0;j<4;j++){ f32x4 z = {0.f,0.f,0.f,0.f}; acc[i][j]=z; }

  const int srow  = (lane >> 2);
  const int sunit = (lane & 3) ^ ((lane >> 3) & 3);   // pre-swizzled source octet
  const unsigned short* Ag0 = A + (int64_t)(m0 + wave*32 + srow)*DD + sunit*8;
  const unsigned short* Ag1 = A + (int64_t)(m0 + wave*32 + 16 + srow)*DD + sunit*8;
  const unsigned short* Wg0 = W + (int64_t)(n0 + wave*32 + srow)*DD + sunit*8;
  const unsigned short* Wg1 = W + (int64_t)(n0 + wave*32 + 16 + srow)*DD + sunit*8;

  auto stage = [&](int buf, int k0){
    gload_lds16(Ag0 + k0, As[buf] + wave*1024);
    gload_lds16(Ag1 + k0, As[buf] + wave*1024 + 512);
    gload_lds16(Wg0 + k0, Ws[buf] + wave*1024);
    gload_lds16(Wg1 + k0, Ws[buf] + wave*1024 + 512);
  };

  const int fro = (g ^ ((l15 >> 1) & 3)) * 8;         // swizzled read offset

  stage(0, 0);
  int it = 0;
  for (int k0 = 0; k0 < DD; k0 += BK, it++){
    const int buf = it & 1;
    __syncthreads();               // stage(buf) landed; prior readers of buf^1 done
    if (k0 + BK < DD) stage(buf^1, k0 + BK);
    bf16x8 af[4], wf[4];
    #pragma unroll
    for (int m=0;m<4;m++) af[m] = *(const bf16x8*)&As[buf][(wr + m*16 + l15)*BK + fro];
    #pragma unroll
    for (int n=0;n<4;n++) wf[n] = *(const bf16x8*)&Ws[buf][(wc + n*16 + l15)*BK + fro];
    #pragma unroll
    for (int m=0;m<4;m++)
      #pragma unroll
      for (int n=0;n<4;n++){
        if constexpr (SWAP)
          acc[m][n] = __builtin_amdgcn_mfma_f32_16x16x32_bf16(wf[n], af[m], acc[m][n], 0,0,0);
        else
          acc[m][n] = __builtin_amdgcn_mfma_f32_16x16x32_bf16(af[m], wf[n], acc[m][n], 0,0,0);
      }
  }

  #pragma unroll
  for (int m=0;m<4;m++)
    #pragma unroll
    for (int n=0;n<4;n++)
      epi(m, n, acc[m][n]);
}

// q/k projection (SWAP): lane=token, regs=4 consecutive dk -> 8B stores
__global__ __launch_bounds__(256)
void qk_gemm(const unsigned short* __restrict__ Xq, const unsigned short* __restrict__ Xk,
             const unsigned short* __restrict__ bWq, const unsigned short* __restrict__ bWk,
             const float* __restrict__ bq, const float* __restrict__ bk,
             unsigned short* __restrict__ qbuf, unsigned short* __restrict__ kbuf)
{
  const int y   = blockIdx.y;          // 0..9
  const int sel = y / 5;
  const int n0  = (y % 5) * BN;
  const int m0  = blockIdx.x * BM;
  const unsigned short* A = sel ? Xk  : Xq;
  const unsigned short* W = sel ? bWk : bWq;
  const float* bb         = sel ? bk  : bq;
  unsigned short* outp    = sel ? kbuf : qbuf;

  const int lane = threadIdx.x & 63, wave = threadIdx.x >> 6;
  const int wr = (wave>>1)*64, wc = (wave&1)*64, l15 = lane&15, g = lane>>4;

  gemm_body<true>(A, W, m0, n0, [&](int m, int n, const f32x4& a){
    const int token = m0 + wr + m*16 + l15;
    const int b = token >> 9, s = token & 511;
    const int wcol0 = n0 + wc + n*16 + g*4;
    const int h = wcol0 >> 6, dk0 = wcol0 & 63;
    f32x4 bv4 = *(const f32x4*)(bb + wcol0);
    u32x2 w;
    w[0] = cvtpk_bf16(a[0]+bv4[0], a[1]+bv4[1]);
    w[1] = cvtpk_bf16(a[2]+bv4[2], a[3]+bv4[3]);
    *(u32x2*)&outp[(((int64_t)(b*HH + h))*SS + s)*DKK + dk0] = w;
  });
}

// v projection (non-SWAP): regs=4 consecutive tokens -> 8B stores over s in [dk][s]
__global__ __launch_bounds__(256)
void v_gemm(const unsigned short* __restrict__ Xv, const unsigned short* __restrict__ bWv,
            const float* __restrict__ bv, unsigned short* __restrict__ vTbuf)
{
  const int n0 = blockIdx.y * BN;
  const int m0 = blockIdx.x * BM;
  const int lane = threadIdx.x & 63, wave = threadIdx.x >> 6;
  const int wr = (wave>>1)*64, wc = (wave&1)*64, l15 = lane&15, g = lane>>4;

  gemm_body<false>(Xv, bWv, m0, n0, [&](int m, int n, const f32x4& a){
    const int row0 = m0 + wr + m*16 + g*4;      // 4 consecutive tokens
    const int b = row0 >> 9, s0 = row0 & 511;
    const int col = n0 + wc + n*16 + l15;
    const int h = col >> 6, dk = col & 63;
    const float bvv = bv[col];
    u32x2 w;
    w[0] = cvtpk_bf16(a[0]+bvv, a[1]+bvv);
    w[1] = cvtpk_bf16(a[2]+bvv, a[3]+bvv);
    *(u32x2*)&vTbuf[(((int64_t)(b*HH + h))*DKK + dk)*SS + s0] = w;
  });
}

// final routing GEMM (SWAP): lane=token, regs=4 consecutive o -> 16B f32x4 stores
__global__ __launch_bounds__(256)
void final_gemm(const unsigned short* __restrict__ A, const unsigned short* __restrict__ W,
                float* __restrict__ outp)
{
  const int m0 = blockIdx.x * BM, n0 = blockIdx.y * BN;
  const int lane = threadIdx.x & 63, wave = threadIdx.x >> 6;
  const int wr = (wave>>1)*64, wc = (wave&1)*64, l15 = lane&15, g = lane>>4;

  gemm_body<true>(A, W, m0, n0, [&](int m, int n, const f32x4& a){
    const int token = m0 + wr + m*16 + l15;
    const int o0 = n0 + wc + n*16 + g*4;
    *(f32x4*)&outp[(int64_t)token*DD + o0] = a;
  });
}

// ---------------- attention (unchanged) ----------------
__global__ __launch_bounds__(256)
void attn_kernel(const unsigned short* __restrict__ qb, const unsigned short* __restrict__ kb,
                 const unsigned short* __restrict__ vT, const unsigned short* __restrict__ biasT,
                 unsigned short* __restrict__ xout)
{
  __shared__ unsigned short SH[20480];   // 40KB: K 2x8KB | V 2x8KB | P 4x2KB
  unsigned short* Kl = SH;               // [2][4096]
  unsigned short* Vl = SH + 8192;        // [2][4096]
  char* Pall = (char*)(SH + 16384);

  const int tid  = threadIdx.x;
  const int lane = tid & 63;
  const int wave = tid >> 6;
  const int l15  = lane & 15;
  const int g    = lane >> 4;

  const int orig = blockIdx.x;
  const int wgid = (orig & 7)*320 + (orig >> 3);   // XCD-chunk swizzle
  const int h  = wgid % 10;
  const int qt = (wgid / 10) & 7;
  const int b  = wgid / 80;
  const int bh = b*HH + h;

  const unsigned short* Q  = qb + (int64_t)bh*SS*DKK;
  const unsigned short* K  = kb + (int64_t)bh*SS*DKK;
  const unsigned short* V  = vT + (int64_t)bh*DKK*SS;
  const unsigned short* Bt = biasT + (int64_t)((b*32 + qt*4 + wave)*32)*256
                           + l15*16 + g*4;

  const int q0 = qt*64 + wave*16;
  char* Pb = Pall + wave*2048;           // 16 rows x 128B

  const int srow8 = lane >> 3;
  const int sunit = (lane & 7) ^ (srow8 & 7);

  bf16x8 qf[2];
  #pragma unroll
  for (int ks=0; ks<2; ks++)
    qf[ks] = *(const bf16x8*)(Q + (q0 + l15)*DKK + ks*32 + g*8);

  auto stage = [&](int c, int buf){
    #pragma unroll
    for (int c2=0;c2<2;c2++){
      const int i = wave*2 + c2;                      // 0..7 across waves
      gload_lds16(K + (int64_t)(c*64 + i*8 + srow8)*DKK + sunit*8,
                  Kl + buf*4096 + i*512);
      gload_lds16(V + (int64_t)(i*8 + srow8)*SS + c*64 + sunit*8,
                  Vl + buf*4096 + i*512);
    }
  };

  float lsum = 0.f;
  f32x4 oacc[4];
  #pragma unroll
  for (int n=0;n<4;n++){ f32x4 z={0.f,0.f,0.f,0.f}; oacc[n]=z; }

  u16x4 bvc[4], bvn[4];
  #pragma unroll
  for (int j=0;j<4;j++) bvc[j] = *(const u16x4*)(Bt + j*256);

  stage(0, 0);
  for (int c = 0; c < 8; c++){
    const int buf = c & 1;
    __syncthreads();                     // stage(c) landed; buf^1 readers done
    if (c < 7){
      stage(c+1, buf^1);
      #pragma unroll
      for (int j=0;j<4;j++) bvn[j] = *(const u16x4*)(Bt + ((c+1)*4 + j)*256);
    }

    f32x4 sc[4];
    #pragma unroll
    for (int j=0;j<4;j++){ f32x4 z={0.f,0.f,0.f,0.f}; sc[j]=z; }
    #pragma unroll
    for (int ks=0; ks<2; ks++){
      #pragma unroll
      for (int j=0;j<4;j++){
        bf16x8 kf = *(const bf16x8*)((char*)(Kl + buf*4096)
                     + (j*16 + l15)*128 + (((ks*4+g) ^ (l15&7))*16));
        sc[j] = __builtin_amdgcn_mfma_f32_16x16x32_bf16(kf, qf[ks], sc[j], 0,0,0);
      }
    }
    #pragma unroll
    for (int j=0;j<4;j++){
      float p[4];
      #pragma unroll
      for (int r=0;r<4;r++){
        float s = __builtin_fmaf(sc[j][r], 0.125f, bf2f(bvc[j][r]));
        p[r] = __expf(s - 8.0f);
        lsum += p[r];
      }
      unsigned int w0 = cvtpk_bf16(p[0], p[1]);
      unsigned int w1 = cvtpk_bf16(p[2], p[3]);
      const int kk = j*16 + g*4;
      const int sw = (kk >> 3) ^ (l15 & 7);
      u32x2 w; w[0]=w0; w[1]=w1;
      *(u32x2*)(Pb + l15*128 + sw*16 + (kk&7)*2) = w;
    }
    #pragma unroll
    for (int kt=0; kt<2; kt++){
      bf16x8 pf = *(const bf16x8*)(Pb + l15*128 + (((kt*4+g) ^ (l15&7))*16));
      #pragma unroll
      for (int n=0;n<4;n++){
        bf16x8 vf = *(const bf16x8*)((char*)(Vl + buf*4096)
                     + (n*16 + l15)*128 + (((kt*4+g) ^ (l15&7))*16));
        oacc[n] = __builtin_amdgcn_mfma_f32_16x16x32_bf16(pf, vf, oacc[n], 0,0,0);
      }
    }
    #pragma unroll
    for (int j=0;j<4;j++) bvc[j] = bvn[j];
  }

  lsum += __shfl_xor(lsum, 16);
  lsum += __shfl_xor(lsum, 32);
  const float inv = 1.0f / lsum;          // valid for q=l15
  float invr[4];
  #pragma unroll
  for (int r=0;r<4;r++) invr[r] = __shfl(inv, g*4 + r);

  #pragma unroll
  for (int n=0;n<4;n++){
    const int dk = n*16 + l15;
    #pragma unroll
    for (int r=0;r<4;r++){
      const int qrow = q0 + g*4 + r;
      const int ntok = b*SS + qrow;
      xout[(int64_t)ntok*DD + h*DKK + dk] = f2bf(oacc[n][r] * invr[r]);
    }
  }
}

// ---------------- gram partial kernel (512 thr, 8 waves, 1 o-tile/wave) ------
// Grid (1024,5) unchanged from R12 (same staging volume); per-wave chain halved.
__global__ __launch_bounds__(512)
void gram_part(const unsigned short* __restrict__ x,
               const unsigned short* __restrict__ RWTf,
               float* __restrict__ Gpart)
{
  __shared__ unsigned short Xl[16*664];   // padded rows (R12 layout)
  __shared__ float Gp[8][16][57];

  const int tid  = threadIdx.x;
  const int lane = tid & 63;
  const int wave = tid >> 6;              // 0..7
  const int l15  = lane & 15;
  const int g    = lane >> 4;
  const int tok0 = blockIdx.x * 16;
  const int oc   = blockIdx.y;            // 0..4

  // stage x[16][640] (10240 elems) with 512 threads: 2 full u32x4 rounds + half round
  #pragma unroll
  for (int rd=0; rd<2; rd++){
    const int idx = rd*4096 + tid*8;
    const int tk  = idx / 640;
    const int cl  = idx - tk*640;
    u32x4 vv = *(const u32x4*)(x + (int64_t)tok0*640 + idx);
    *(u32x4*)&Xl[tk*664 + cl] = vv;
  }
  if (tid < 256){
    const int idx = 8192 + tid*8;
    const int tk  = idx / 640;
    const int cl  = idx - tk*640;
    u32x4 vv = *(const u32x4*)(x + (int64_t)tok0*640 + idx);
    *(u32x4*)&Xl[tk*664 + cl] = vv;
  }
  __syncthreads();

  const int oTile = oc*8 + wave;          // 0..39
  const unsigned short* base = RWTf + (size_t)oTile*10240;

  f32x4 P[10];
  #pragma unroll
  for (int r=0;r<10;r++){ f32x4 z={0.f,0.f,0.f,0.f}; P[r]=z; }

  // manual 1-r-step prefetch of af (2 x 16B in flight; hides L2 latency)
  bf16x8 afc0 = *(const bf16x8*)&base[0*512 + lane*8];
  bf16x8 afc1 = *(const bf16x8*)&base[1*512 + lane*8];
  #pragma unroll
  for (int r=0;r<10;r++){
    bf16x8 afn0, afn1;
    if (r < 9){
      afn0 = *(const bf16x8*)&base[(2*r+2)*512 + lane*8];
      afn1 = *(const bf16x8*)&base[(2*r+3)*512 + lane*8];
    }
    bf16x8 xf0 = *(const bf16x8*)&Xl[l15*664 + r*64 + g*8];
    bf16x8 xf1 = *(const bf16x8*)&Xl[l15*664 + r*64 + 32 + g*8];
    P[r] = __builtin_amdgcn_mfma_f32_16x16x32_bf16(afc0, xf0, P[r], 0,0,0);
    P[r] = __builtin_amdgcn_mfma_f32_16x16x32_bf16(afc1, xf1, P[r], 0,0,0);
    afc0 = afn0; afc1 = afn1;
  }

  float Gacc[55];
  #pragma unroll
  for (int p=0;p<55;p++) Gacc[p]=0.f;
  #pragma unroll
  for (int r=0;r<10;r++)
    #pragma unroll
    for (int rp=r; rp<10; rp++){
      const int T = r*10 - r*(r-1)/2 + (rp-r);
      Gacc[T] += P[r][0]*P[rp][0] + P[r][1]*P[rp][1]
               + P[r][2]*P[rp][2] + P[r][3]*P[rp][3];
    }
  #pragma unroll
  for (int p=0;p<55;p++){
    Gacc[p] += __shfl_xor(Gacc[p], 16);
    Gacc[p] += __shfl_xor(Gacc[p], 32);
  }
  if (lane < 16){
    #pragma unroll
    for (int p=0;p<55;p++) Gp[wave][lane][p] = Gacc[p];
  }
  __syncthreads();
  {
    const int gtok = tid & 15;
    for (int p = tid>>4; p < 55; p += 32){
      float s = 0.f;
      #pragma unroll
      for (int w2=0; w2<8; w2++) s += Gp[w2][gtok][p];
      Gpart[((size_t)oc*NTOK + tok0 + gtok)*56 + p] = s;
    }
  }
}

// ---------------- routing recurrence + xw ----------------
__global__ __launch_bounds__(256)
void route_xw(const float* __restrict__ Gpart, const unsigned short* __restrict__ x,
              unsigned short* __restrict__ xw)
{
  __shared__ float Gfin[16][57];
  __shared__ float Pr[16][10];
  __shared__ float Dm[16][10];
  __shared__ float Lg[16][10];
  __shared__ float wl[16][10];

  const int tid  = threadIdx.x;
  const int tok0 = blockIdx.x * 16;

  {
    const int gtok = tid & 15;
    for (int p = tid>>4; p < 55; p += 16){
      float s = 0.f;
      #pragma unroll
      for (int oc=0; oc<5; oc++)
        s += Gpart[((size_t)oc*NTOK + tok0 + gtok)*56 + p];
      Gfin[gtok][p] = s;
    }
  }
  __syncthreads();

  const int tok = tid >> 4, rp = tid & 15;
  const bool act = rp < 10;
  float grow[10]; float Lr = 0.f;
  if (act){
    #pragma unroll
    for (int r=0;r<10;r++){
      const int lo = r < rp ? r : rp, hi = r < rp ? rp : r;
      grow[r] = Gfin[tok][lo*10 - lo*(lo-1)/2 + (hi-lo)];
    }
    Pr[tok][rp] = 0.1f;
  }
  __syncthreads();
  for (int it=0; it<3; it++){
    float d = 0.f;
    if (act){
      #pragma unroll
      for (int r=0;r<10;r++) d += grow[r]*Pr[tok][r];
      Dm[tok][rp] = d;
    }
    __syncthreads();
    if (act){
      float sn = 0.f;
      #pragma unroll
      for (int r=0;r<10;r++) sn += Dm[tok][r]*Pr[tok][r];
      const float sc = (sn/(1.f+sn))*rsqrtf(sn+1e-9f);
      if (it < 2){ Lr += sc*d; Lg[tok][rp] = Lr; }
      else        wl[tok][rp] = sc*Pr[tok][rp];
    }
    __syncthreads();
    if (it < 2){
      if (act){
        float mx = Lg[tok][0];
        #pragma unroll
        for (int r=1;r<10;r++) mx = fmaxf(mx, Lg[tok][r]);
        float se = 0.f;
        #pragma unroll
        for (int r=0;r<10;r++) se += __expf(Lg[tok][r]-mx);
        Pr[tok][rp] = __expf(Lr-mx)/se;
      }
      __syncthreads();
    }
  }

  // xw = x * w, fully coalesced 8-elem chunks (chunk never crosses a 64-col head seg)
  #pragma unroll
  for (int e=0; e<5; e++){
    const int idx = e*2048 + tid*8;
    const int tk  = idx / 640;
    const int cl  = idx - tk*640;
    const float w = wl[tk][cl>>6];
    u16x4 a = *(const u16x4*)(x + (int64_t)tok0*640 + idx);
    u16x4 b = *(const u16x4*)(x + (int64_t)tok0*640 + idx + 4);
    u32x4 o;
    o[0] = cvtpk_bf16(bf2f(a[0])*w, bf2f(a[1])*w);
    o[1] = cvtpk_bf16(bf2f(a[2])*w, bf2f(a[3])*w);
    o[2] = cvtpk_bf16(bf2f(b[0])*w, bf2f(b[1])*w);
    o[3] = cvtpk_bf16(bf2f(b[2])*w, bf2f(b[3])*w);
    *(u32x4*)&xw[(int64_t)tok0*640 + idx] = o;
  }
}

// ---------------- launch ----------------
extern "C" void kernel_launch(void* const* d_in, const int* in_sizes, int n_in,
                              void* d_out, int out_size, void* d_ws, size_t ws_size,
                              hipStream_t stream)
{
  (void)in_sizes; (void)n_in; (void)out_size; (void)ws_size;
  const float* q    = (const float*)d_in[0];
  const float* k    = (const float*)d_in[1];
  const float* v    = (const float*)d_in[2];
  const int*   mask = (const int*)d_in[3];
  const float* adj  = (const float*)d_in[4];
  const int*   layer= (const int*)d_in[5];
  const float* Wq   = (const float*)d_in[6];
  const float* bq   = (const float*)d_in[7];
  const float* Wk   = (const float*)d_in[8];
  const float* bk   = (const float*)d_in[9];
  const float* Wv   = (const float*)d_in[10];
  const float* bv   = (const float*)d_in[11];
  const float* rw   = (const float*)d_in[12];

  char* ws = (char*)d_ws;
  size_t off = 0;
  auto alloc = [&](size_t sz)->char*{ char* p = ws + off; off += (sz + 255) & ~(size_t)255; return p; };
  const size_t SZX = (size_t)NTOK*DD*2;
  unsigned short* Xq    = (unsigned short*)alloc(SZX);
  unsigned short* Xk    = (unsigned short*)alloc(SZX);
  unsigned short* Xv    = (unsigned short*)alloc(SZX);
  unsigned short* bWq   = (unsigned short*)alloc((size_t)DD*DD*2);
  unsigned short* bWk   = (unsigned short*)alloc((size_t)DD*DD*2);
  unsigned short* bWv   = (unsigned short*)alloc((size_t)DD*DD*2);
  unsigned short* bRWT  = (unsigned short*)alloc((size_t)DD*DD*2);
  unsigned short* bRWTf = (unsigned short*)alloc((size_t)DD*DD*2);
  unsigned short* qbuf  = (unsigned short*)alloc(SZX);
  unsigned short* kbuf  = (unsigned short*)alloc(SZX);
  unsigned short* vTbuf = (unsigned short*)alloc(SZX);
  unsigned short* biasb = (unsigned short*)alloc((size_t)BB*SS*SS*2);
  float*          Gpart = (float*)alloc((size_t)5*NTOK*56*4);
  // aliases (provably dead at reuse time, stream-ordered):
  unsigned short* xout  = Xq;    // Xq dead after qk_gemm
  unsigned short* xw    = Xk;    // Xk dead after qk_gemm

  prep_kernel<<<5696,256,0,stream>>>(q,k,v,mask,adj,layer,Wq,Wk,Wv,rw,
                                     Xq,Xk,Xv,bWq,bWk,bWv,bRWT,bRWTf,biasb);

  dim3 gqk(NTOK/BM, 10);
  qk_gemm<<<gqk,256,0,stream>>>(Xq,Xk,bWq,bWk,bq,bk,qbuf,kbuf);
  dim3 gv(NTOK/BM, 5);
  v_gemm<<<gv,256,0,stream>>>(Xv,bWv,bv,vTbuf);

  attn_kernel<<<2560,256,0,stream>>>(qbuf,kbuf,vTbuf,biasb,xout);

  dim3 gp(NTOK/16, 5);
  gram_part<<<gp,512,0,stream>>>(xout,bRWTf,Gpart);
  route_xw<<<NTOK/16,256,0,stream>>>(Gpart,xout,xw);

  dim3 gf(NTOK/BM, DD/BN);
  final_gemm<<<gf,256,0,stream>>>(xw,bRWT,(float*)d_out);
}

// Round 18
// 285.319 us; speedup vs baseline: 1.0751x; 1.0751x over previous
//
#include <hip/hip_runtime.h>
#include <stdint.h>

#define BB 32
#define SS 512
#define DD 640
#define HH 10
#define DKK 64
#define NTOK (BB*SS)   // 16384

using f32x4  = __attribute__((ext_vector_type(4))) float;
using bf16x8 = __attribute__((ext_vector_type(8))) __bf16;
using u32x4  = __attribute__((ext_vector_type(4))) unsigned int;
using u32x2  = __attribute__((ext_vector_type(2))) unsigned int;
using u16x4  = __attribute__((ext_vector_type(4))) unsigned short;
using i32x4  = __attribute__((ext_vector_type(4))) int;

__device__ inline unsigned short f2bf(float f){
  union { float f; unsigned int u; } v; v.f=f;
  unsigned int u=v.u;
  u += 0x7FFFu + ((u>>16)&1u);
  return (unsigned short)(u>>16);
}
__device__ inline float bf2f(unsigned short s){
  union { unsigned int u; float f; } v; v.u = ((unsigned int)s)<<16;
  return v.f;
}
__device__ inline unsigned int cvtpk_bf16(float lo, float hi){
  unsigned int r;
  asm volatile("v_cvt_pk_bf16_f32 %0, %1, %2" : "=v"(r) : "v"(lo), "v"(hi));
  return r;
}
__device__ inline void gload_lds16(const void* g, void* l){
  __builtin_amdgcn_global_load_lds(
      (const __attribute__((address_space(1))) unsigned int*)g,
      (__attribute__((address_space(3))) unsigned int*)l, 16, 0, 0);
}

// ---------------- prep: per-array qkv convert | weights | bias ---------------
// grid 5697: [0,2049) one array per block (2-stream copy pattern, m13);
// [2049,3649) weights; [3649,5697) bias tiles
__global__ void prep_kernel(const float* __restrict__ q, const float* __restrict__ k,
                            const float* __restrict__ v,
                            const int* __restrict__ mask, const float* __restrict__ adj,
                            const int* __restrict__ layer,
                            const float* __restrict__ wq, const float* __restrict__ wk,
                            const float* __restrict__ wv, const float* __restrict__ rw,
                            unsigned short* __restrict__ xq, unsigned short* __restrict__ xk,
                            unsigned short* __restrict__ xv,
                            unsigned short* __restrict__ bwq, unsigned short* __restrict__ bwk,
                            unsigned short* __restrict__ bwv, unsigned short* __restrict__ brwt,
                            unsigned short* __restrict__ brwtf,
                            unsigned short* __restrict__ biasT)
{
  const int bid = blockIdx.x;
  const int tid = threadIdx.x;
  if (bid < 2049){
    const int sel = bid % 3;
    const float* src        = sel==0 ? q  : sel==1 ? k  : v;
    unsigned short* dst     = sel==0 ? xq : sel==1 ? xk : xv;
    int i = (bid/3)*256 + tid;
    const int n4 = (NTOK*DD)/4;
    for (; i < n4; i += 683*256){
      f32x4 a = ((const f32x4*)src)[i];
      u16x4 r;
      #pragma unroll
      for (int j=0;j<4;j++) r[j]=f2bf(a[j]);
      ((u16x4*)dst)[i]=r;
    }
  } else if (bid < 3649){
    const int i = (bid-2049)*256 + tid;
    if (i < DD*DD){
      bwq[i]=f2bf(wq[i]); bwk[i]=f2bf(wk[i]); bwv[i]=f2bf(wv[i]);
      unsigned short rv = f2bf(rw[i]);
      const int kk = i / DD;       // r*64 + ii
      const int o  = i % DD;
      brwt[o*DD + kk] = rv;        // final_gemm W operand (rows=o, cols=k)
      const int r  = kk >> 6, ii = kk & 63;
      const int ks = ii >> 5, rem = ii & 31, g = rem >> 3, j = rem & 7;
      const int oT = o >> 4, l15o = o & 15;
      brwtf[(size_t)((oT*10 + r)*2 + ks)*512 + (g*16 + l15o)*8 + j] = rv;
    }
  } else {
    float sc = 1.0f/(float)(layer[0]+1);
    int i = (bid-3649)*256 + tid;
    const int n4 = (BB*SS*SS)/4;
    for (; i < n4; i += 2048*256){
      i32x4 m = ((const i32x4*)mask)[i];
      f32x4 a = ((const f32x4*)adj)[i];
      u16x4 r;
      #pragma unroll
      for (int j=0;j<4;j++) r[j] = m[j] ? f2bf(a[j]*sc) : f2bf(-1e9f);
      const int e  = i*4;
      const int bb = e >> 18;
      const int qq = (e >> 9) & 511;
      const int kk = e & 511;
      const int idx = (((bb*32 + (qq>>4))*32 + (kk>>4))<<8) + ((qq&15)<<4) + (kk&15);
      *(u16x4*)(biasT + idx) = r;
    }
  }
}

// ---------------- GEMM body (128x128, BK=32, 256 thr, dbuf) ------------------
#define BM 128
#define BN 128
#define BK 32

template<bool SWAP, typename EPI>
__device__ inline void gemm_body(const unsigned short* __restrict__ A,
                                 const unsigned short* __restrict__ W,
                                 int m0, int n0, EPI&& epi)
{
  __shared__ unsigned short As[2][BM*BK];
  __shared__ unsigned short Ws[2][BN*BK];
  const int tid  = threadIdx.x;
  const int lane = tid & 63;
  const int wave = tid >> 6;
  const int wr   = (wave >> 1) * 64;
  const int wc   = (wave & 1) * 64;
  const int l15  = lane & 15;
  const int g    = lane >> 4;

  f32x4 acc[4][4];
  #pragma unroll
  for (int i=0;i<4;i++)
    #pragma unroll
    for (int j=0;j<4;j++){ f32x4 z = {0.f,0.f,0.f,0.f}; acc[i][j]=z; }

  const int srow  = (lane >> 2);
  const int sunit = (lane & 3) ^ ((lane >> 3) & 3);   // pre-swizzled source octet
  const unsigned short* Ag0 = A + (int64_t)(m0 + wave*32 + srow)*DD + sunit*8;
  const unsigned short* Ag1 = A + (int64_t)(m0 + wave*32 + 16 + srow)*DD + sunit*8;
  const unsigned short* Wg0 = W + (int64_t)(n0 + wave*32 + srow)*DD + sunit*8;
  const unsigned short* Wg1 = W + (int64_t)(n0 + wave*32 + 16 + srow)*DD + sunit*8;

  auto stage = [&](int buf, int k0){
    gload_lds16(Ag0 + k0, As[buf] + wave*1024);
    gload_lds16(Ag1 + k0, As[buf] + wave*1024 + 512);
    gload_lds16(Wg0 + k0, Ws[buf] + wave*1024);
    gload_lds16(Wg1 + k0, Ws[buf] + wave*1024 + 512);
  };

  const int fro = (g ^ ((l15 >> 1) & 3)) * 8;         // swizzled read offset

  stage(0, 0);
  int it = 0;
  for (int k0 = 0; k0 < DD; k0 += BK, it++){
    const int buf = it & 1;
    __syncthreads();               // stage(buf) landed; prior readers of buf^1 done
    if (k0 + BK < DD) stage(buf^1, k0 + BK);
    bf16x8 af[4], wf[4];
    #pragma unroll
    for (int m=0;m<4;m++) af[m] = *(const bf16x8*)&As[buf][(wr + m*16 + l15)*BK + fro];
    #pragma unroll
    for (int n=0;n<4;n++) wf[n] = *(const bf16x8*)&Ws[buf][(wc + n*16 + l15)*BK + fro];
    #pragma unroll
    for (int m=0;m<4;m++)
      #pragma unroll
      for (int n=0;n<4;n++){
        if constexpr (SWAP)
          acc[m][n] = __builtin_amdgcn_mfma_f32_16x16x32_bf16(wf[n], af[m], acc[m][n], 0,0,0);
        else
          acc[m][n] = __builtin_amdgcn_mfma_f32_16x16x32_bf16(af[m], wf[n], acc[m][n], 0,0,0);
      }
  }

  #pragma unroll
  for (int m=0;m<4;m++)
    #pragma unroll
    for (int n=0;n<4;n++)
      epi(m, n, acc[m][n]);
}

// q/k projection (SWAP): lane=token, regs=4 consecutive dk -> 8B stores
__global__ __launch_bounds__(256)
void qk_gemm(const unsigned short* __restrict__ Xq, const unsigned short* __restrict__ Xk,
             const unsigned short* __restrict__ bWq, const unsigned short* __restrict__ bWk,
             const float* __restrict__ bq, const float* __restrict__ bk,
             unsigned short* __restrict__ qbuf, unsigned short* __restrict__ kbuf)
{
  const int y   = blockIdx.y;          // 0..9
  const int sel = y / 5;
  const int n0  = (y % 5) * BN;
  const int m0  = blockIdx.x * BM;
  const unsigned short* A = sel ? Xk  : Xq;
  const unsigned short* W = sel ? bWk : bWq;
  const float* bb         = sel ? bk  : bq;
  unsigned short* outp    = sel ? kbuf : qbuf;

  const int lane = threadIdx.x & 63, wave = threadIdx.x >> 6;
  const int wr = (wave>>1)*64, wc = (wave&1)*64, l15 = lane&15, g = lane>>4;

  gemm_body<true>(A, W, m0, n0, [&](int m, int n, const f32x4& a){
    const int token = m0 + wr + m*16 + l15;
    const int b = token >> 9, s = token & 511;
    const int wcol0 = n0 + wc + n*16 + g*4;
    const int h = wcol0 >> 6, dk0 = wcol0 & 63;
    f32x4 bv4 = *(const f32x4*)(bb + wcol0);
    u32x2 w;
    w[0] = cvtpk_bf16(a[0]+bv4[0], a[1]+bv4[1]);
    w[1] = cvtpk_bf16(a[2]+bv4[2], a[3]+bv4[3]);
    *(u32x2*)&outp[(((int64_t)(b*HH + h))*SS + s)*DKK + dk0] = w;
  });
}

// v projection (non-SWAP): regs=4 consecutive tokens -> 8B stores over s in [dk][s]
__global__ __launch_bounds__(256)
void v_gemm(const unsigned short* __restrict__ Xv, const unsigned short* __restrict__ bWv,
            const float* __restrict__ bv, unsigned short* __restrict__ vTbuf)
{
  const int n0 = blockIdx.y * BN;
  const int m0 = blockIdx.x * BM;
  const int lane = threadIdx.x & 63, wave = threadIdx.x >> 6;
  const int wr = (wave>>1)*64, wc = (wave&1)*64, l15 = lane&15, g = lane>>4;

  gemm_body<false>(Xv, bWv, m0, n0, [&](int m, int n, const f32x4& a){
    const int row0 = m0 + wr + m*16 + g*4;      // 4 consecutive tokens
    const int b = row0 >> 9, s0 = row0 & 511;
    const int col = n0 + wc + n*16 + l15;
    const int h = col >> 6, dk = col & 63;
    const float bvv = bv[col];
    u32x2 w;
    w[0] = cvtpk_bf16(a[0]+bvv, a[1]+bvv);
    w[1] = cvtpk_bf16(a[2]+bvv, a[3]+bvv);
    *(u32x2*)&vTbuf[(((int64_t)(b*HH + h))*DKK + dk)*SS + s0] = w;
  });
}

// final routing GEMM (SWAP): lane=token, regs=4 consecutive o -> 16B f32x4 stores
__global__ __launch_bounds__(256)
void final_gemm(const unsigned short* __restrict__ A, const unsigned short* __restrict__ W,
                float* __restrict__ outp)
{
  const int m0 = blockIdx.x * BM, n0 = blockIdx.y * BN;
  const int lane = threadIdx.x & 63, wave = threadIdx.x >> 6;
  const int wr = (wave>>1)*64, wc = (wave&1)*64, l15 = lane&15, g = lane>>4;

  gemm_body<true>(A, W, m0, n0, [&](int m, int n, const f32x4& a){
    const int token = m0 + wr + m*16 + l15;
    const int o0 = n0 + wc + n*16 + g*4;
    *(f32x4*)&outp[(int64_t)token*DD + o0] = a;
  });
}

// ---------------- attention (unchanged) ----------------
__global__ __launch_bounds__(256)
void attn_kernel(const unsigned short* __restrict__ qb, const unsigned short* __restrict__ kb,
                 const unsigned short* __restrict__ vT, const unsigned short* __restrict__ biasT,
                 unsigned short* __restrict__ xout)
{
  __shared__ unsigned short SH[20480];   // 40KB: K 2x8KB | V 2x8KB | P 4x2KB
  unsigned short* Kl = SH;               // [2][4096]
  unsigned short* Vl = SH + 8192;        // [2][4096]
  char* Pall = (char*)(SH + 16384);

  const int tid  = threadIdx.x;
  const int lane = tid & 63;
  const int wave = tid >> 6;
  const int l15  = lane & 15;
  const int g    = lane >> 4;

  const int orig = blockIdx.x;
  const int wgid = (orig & 7)*320 + (orig >> 3);   // XCD-chunk swizzle
  const int h  = wgid % 10;
  const int qt = (wgid / 10) & 7;
  const int b  = wgid / 80;
  const int bh = b*HH + h;

  const unsigned short* Q  = qb + (int64_t)bh*SS*DKK;
  const unsigned short* K  = kb + (int64_t)bh*SS*DKK;
  const unsigned short* V  = vT + (int64_t)bh*DKK*SS;
  const unsigned short* Bt = biasT + (int64_t)((b*32 + qt*4 + wave)*32)*256
                           + l15*16 + g*4;

  const int q0 = qt*64 + wave*16;
  char* Pb = Pall + wave*2048;           // 16 rows x 128B

  const int srow8 = lane >> 3;
  const int sunit = (lane & 7) ^ (srow8 & 7);

  bf16x8 qf[2];
  #pragma unroll
  for (int ks=0; ks<2; ks++)
    qf[ks] = *(const bf16x8*)(Q + (q0 + l15)*DKK + ks*32 + g*8);

  auto stage = [&](int c, int buf){
    #pragma unroll
    for (int c2=0;c2<2;c2++){
      const int i = wave*2 + c2;                      // 0..7 across waves
      gload_lds16(K + (int64_t)(c*64 + i*8 + srow8)*DKK + sunit*8,
                  Kl + buf*4096 + i*512);
      gload_lds16(V + (int64_t)(i*8 + srow8)*SS + c*64 + sunit*8,
                  Vl + buf*4096 + i*512);
    }
  };

  float lsum = 0.f;
  f32x4 oacc[4];
  #pragma unroll
  for (int n=0;n<4;n++){ f32x4 z={0.f,0.f,0.f,0.f}; oacc[n]=z; }

  u16x4 bvc[4], bvn[4];
  #pragma unroll
  for (int j=0;j<4;j++) bvc[j] = *(const u16x4*)(Bt + j*256);

  stage(0, 0);
  for (int c = 0; c < 8; c++){
    const int buf = c & 1;
    __syncthreads();                     // stage(c) landed; buf^1 readers done
    if (c < 7){
      stage(c+1, buf^1);
      #pragma unroll
      for (int j=0;j<4;j++) bvn[j] = *(const u16x4*)(Bt + ((c+1)*4 + j)*256);
    }

    f32x4 sc[4];
    #pragma unroll
    for (int j=0;j<4;j++){ f32x4 z={0.f,0.f,0.f,0.f}; sc[j]=z; }
    #pragma unroll
    for (int ks=0; ks<2; ks++){
      #pragma unroll
      for (int j=0;j<4;j++){
        bf16x8 kf = *(const bf16x8*)((char*)(Kl + buf*4096)
                     + (j*16 + l15)*128 + (((ks*4+g) ^ (l15&7))*16));
        sc[j] = __builtin_amdgcn_mfma_f32_16x16x32_bf16(kf, qf[ks], sc[j], 0,0,0);
      }
    }
    #pragma unroll
    for (int j=0;j<4;j++){
      float p[4];
      #pragma unroll
      for (int r=0;r<4;r++){
        float s = __builtin_fmaf(sc[j][r], 0.125f, bf2f(bvc[j][r]));
        p[r] = __expf(s - 8.0f);
        lsum += p[r];
      }
      unsigned int w0 = cvtpk_bf16(p[0], p[1]);
      unsigned int w1 = cvtpk_bf16(p[2], p[3]);
      const int kk = j*16 + g*4;
      const int sw = (kk >> 3) ^ (l15 & 7);
      u32x2 w; w[0]=w0; w[1]=w1;
      *(u32x2*)(Pb + l15*128 + sw*16 + (kk&7)*2) = w;
    }
    #pragma unroll
    for (int kt=0; kt<2; kt++){
      bf16x8 pf = *(const bf16x8*)(Pb + l15*128 + (((kt*4+g) ^ (l15&7))*16));
      #pragma unroll
      for (int n=0;n<4;n++){
        bf16x8 vf = *(const bf16x8*)((char*)(Vl + buf*4096)
                     + (n*16 + l15)*128 + (((kt*4+g) ^ (l15&7))*16));
        oacc[n] = __builtin_amdgcn_mfma_f32_16x16x32_bf16(pf, vf, oacc[n], 0,0,0);
      }
    }
    #pragma unroll
    for (int j=0;j<4;j++) bvc[j] = bvn[j];
  }

  lsum += __shfl_xor(lsum, 16);
  lsum += __shfl_xor(lsum, 32);
  const float inv = 1.0f / lsum;          // valid for q=l15
  float invr[4];
  #pragma unroll
  for (int r=0;r<4;r++) invr[r] = __shfl(inv, g*4 + r);

  #pragma unroll
  for (int n=0;n<4;n++){
    const int dk = n*16 + l15;
    #pragma unroll
    for (int r=0;r<4;r++){
      const int qrow = q0 + g*4 + r;
      const int ntok = b*SS + qrow;
      xout[(int64_t)ntok*DD + h*DKK + dk] = f2bf(oacc[n][r] * invr[r]);
    }
  }
}

// ---------------- gram partial kernel (R12 exact) ----------------
__global__ __launch_bounds__(256)
void gram_part(const unsigned short* __restrict__ x,
               const unsigned short* __restrict__ RWTf,
               float* __restrict__ Gpart)
{
  __shared__ unsigned short Xl[16*664];   // padded rows
  __shared__ float Gp[4][16][57];

  const int tid  = threadIdx.x;
  const int lane = tid & 63;
  const int wave = tid >> 6;
  const int l15  = lane & 15;
  const int g    = lane >> 4;
  const int tok0 = blockIdx.x * 16;
  const int oc   = blockIdx.y;            // 0..4

  #pragma unroll
  for (int rd=0; rd<5; rd++){
    const int idx = rd*2048 + tid*8;
    const int tk  = idx / 640;
    const int cl  = idx - tk*640;
    u32x4 vv = *(const u32x4*)(x + (int64_t)tok0*640 + idx);
    *(u32x4*)&Xl[tk*664 + cl] = vv;
  }
  __syncthreads();

  float Gacc[55];
  #pragma unroll
  for (int p=0;p<55;p++) Gacc[p]=0.f;

  #pragma unroll
  for (int ot2=0; ot2<2; ot2++){
    const int oTile = oc*8 + wave*2 + ot2;
    const unsigned short* base = RWTf + (size_t)oTile*10240;  // 10*2*512
    f32x4 P[10];
    #pragma unroll
    for (int r=0;r<10;r++){ f32x4 z={0.f,0.f,0.f,0.f}; P[r]=z; }
    #pragma unroll
    for (int r=0;r<10;r++){
      #pragma unroll
      for (int ks=0;ks<2;ks++){
        bf16x8 af = *(const bf16x8*)&base[(r*2+ks)*512 + lane*8];   // coalesced 1KB
        bf16x8 xf = *(const bf16x8*)&Xl[l15*664 + r*64 + ks*32 + g*8];
        P[r] = __builtin_amdgcn_mfma_f32_16x16x32_bf16(af, xf, P[r], 0,0,0);
      }
    }
    #pragma unroll
    for (int r=0;r<10;r++)
      #pragma unroll
      for (int rp=r; rp<10; rp++){
        const int T = r*10 - r*(r-1)/2 + (rp-r);
        Gacc[T] += P[r][0]*P[rp][0] + P[r][1]*P[rp][1]
                 + P[r][2]*P[rp][2] + P[r][3]*P[rp][3];
      }
  }
  #pragma unroll
  for (int p=0;p<55;p++){
    Gacc[p] += __shfl_xor(Gacc[p], 16);
    Gacc[p] += __shfl_xor(Gacc[p], 32);
  }
  if (lane < 16){
    #pragma unroll
    for (int p=0;p<55;p++) Gp[wave][lane][p] = Gacc[p];
  }
  __syncthreads();
  {
    const int gtok = tid & 15;
    for (int p = tid>>4; p < 55; p += 16)
      Gpart[((size_t)oc*NTOK + tok0 + gtok)*56 + p]
        = Gp[0][gtok][p]+Gp[1][gtok][p]+Gp[2][gtok][p]+Gp[3][gtok][p];
  }
}

// ---------------- routing recurrence + xw ----------------
__global__ __launch_bounds__(256)
void route_xw(const float* __restrict__ Gpart, const unsigned short* __restrict__ x,
              unsigned short* __restrict__ xw)
{
  __shared__ float Gfin[16][57];
  __shared__ float Pr[16][10];
  __shared__ float Dm[16][10];
  __shared__ float Lg[16][10];
  __shared__ float wl[16][10];

  const int tid  = threadIdx.x;
  const int tok0 = blockIdx.x * 16;

  {
    const int gtok = tid & 15;
    for (int p = tid>>4; p < 55; p += 16){
      float s = 0.f;
      #pragma unroll
      for (int oc=0; oc<5; oc++)
        s += Gpart[((size_t)oc*NTOK + tok0 + gtok)*56 + p];
      Gfin[gtok][p] = s;
    }
  }
  __syncthreads();

  const int tok = tid >> 4, rp = tid & 15;
  const bool act = rp < 10;
  float grow[10]; float Lr = 0.f;
  if (act){
    #pragma unroll
    for (int r=0;r<10;r++){
      const int lo = r < rp ? r : rp, hi = r < rp ? rp : r;
      grow[r] = Gfin[tok][lo*10 - lo*(lo-1)/2 + (hi-lo)];
    }
    Pr[tok][rp] = 0.1f;
  }
  __syncthreads();
  for (int it=0; it<3; it++){
    float d = 0.f;
    if (act){
      #pragma unroll
      for (int r=0;r<10;r++) d += grow[r]*Pr[tok][r];
      Dm[tok][rp] = d;
    }
    __syncthreads();
    if (act){
      float sn = 0.f;
      #pragma unroll
      for (int r=0;r<10;r++) sn += Dm[tok][r]*Pr[tok][r];
      const float sc = (sn/(1.f+sn))*rsqrtf(sn+1e-9f);
      if (it < 2){ Lr += sc*d; Lg[tok][rp] = Lr; }
      else        wl[tok][rp] = sc*Pr[tok][rp];
    }
    __syncthreads();
    if (it < 2){
      if (act){
        float mx = Lg[tok][0];
        #pragma unroll
        for (int r=1;r<10;r++) mx = fmaxf(mx, Lg[tok][r]);
        float se = 0.f;
        #pragma unroll
        for (int r=0;r<10;r++) se += __expf(Lg[tok][r]-mx);
        Pr[tok][rp] = __expf(Lr-mx)/se;
      }
      __syncthreads();
    }
  }

  // xw = x * w, fully coalesced 8-elem chunks (chunk never crosses a 64-col head seg)
  #pragma unroll
  for (int e=0; e<5; e++){
    const int idx = e*2048 + tid*8;
    const int tk  = idx / 640;
    const int cl  = idx - tk*640;
    const float w = wl[tk][cl>>6];
    u16x4 a = *(const u16x4*)(x + (int64_t)tok0*640 + idx);
    u16x4 b = *(const u16x4*)(x + (int64_t)tok0*640 + idx + 4);
    u32x4 o;
    o[0] = cvtpk_bf16(bf2f(a[0])*w, bf2f(a[1])*w);
    o[1] = cvtpk_bf16(bf2f(a[2])*w, bf2f(a[3])*w);
    o[2] = cvtpk_bf16(bf2f(b[0])*w, bf2f(b[1])*w);
    o[3] = cvtpk_bf16(bf2f(b[2])*w, bf2f(b[3])*w);
    *(u32x4*)&xw[(int64_t)tok0*640 + idx] = o;
  }
}

// ---------------- launch ----------------
extern "C" void kernel_launch(void* const* d_in, const int* in_sizes, int n_in,
                              void* d_out, int out_size, void* d_ws, size_t ws_size,
                              hipStream_t stream)
{
  (void)in_sizes; (void)n_in; (void)out_size; (void)ws_size;
  const float* q    = (const float*)d_in[0];
  const float* k    = (const float*)d_in[1];
  const float* v    = (const float*)d_in[2];
  const int*   mask = (const int*)d_in[3];
  const float* adj  = (const float*)d_in[4];
  const int*   layer= (const int*)d_in[5];
  const float* Wq   = (const float*)d_in[6];
  const float* bq   = (const float*)d_in[7];
  const float* Wk   = (const float*)d_in[8];
  const float* bk   = (const float*)d_in[9];
  const float* Wv   = (const float*)d_in[10];
  const float* bv   = (const float*)d_in[11];
  const float* rw   = (const float*)d_in[12];

  char* ws = (char*)d_ws;
  size_t off = 0;
  auto alloc = [&](size_t sz)->char*{ char* p = ws + off; off += (sz + 255) & ~(size_t)255; return p; };
  const size_t SZX = (size_t)NTOK*DD*2;
  unsigned short* Xq    = (unsigned short*)alloc(SZX);
  unsigned short* Xk    = (unsigned short*)alloc(SZX);
  unsigned short* Xv    = (unsigned short*)alloc(SZX);
  unsigned short* bWq   = (unsigned short*)alloc((size_t)DD*DD*2);
  unsigned short* bWk   = (unsigned short*)alloc((size_t)DD*DD*2);
  unsigned short* bWv   = (unsigned short*)alloc((size_t)DD*DD*2);
  unsigned short* bRWT  = (unsigned short*)alloc((size_t)DD*DD*2);
  unsigned short* bRWTf = (unsigned short*)alloc((size_t)DD*DD*2);
  unsigned short* qbuf  = (unsigned short*)alloc(SZX);
  unsigned short* kbuf  = (unsigned short*)alloc(SZX);
  unsigned short* vTbuf = (unsigned short*)alloc(SZX);
  unsigned short* biasb = (unsigned short*)alloc((size_t)BB*SS*SS*2);
  float*          Gpart = (float*)alloc((size_t)5*NTOK*56*4);
  // aliases (provably dead at reuse time, stream-ordered):
  unsigned short* xout  = Xq;    // Xq dead after qk_gemm
  unsigned short* xw    = Xk;    // Xk dead after qk_gemm

  prep_kernel<<<5697,256,0,stream>>>(q,k,v,mask,adj,layer,Wq,Wk,Wv,rw,
                                     Xq,Xk,Xv,bWq,bWk,bWv,bRWT,bRWTf,biasb);

  dim3 gqk(NTOK/BM, 10);
  qk_gemm<<<gqk,256,0,stream>>>(Xq,Xk,bWq,bWk,bq,bk,qbuf,kbuf);
  dim3 gv(NTOK/BM, 5);
  v_gemm<<<gv,256,0,stream>>>(Xv,bWv,bv,vTbuf);

  attn_kernel<<<2560,256,0,stream>>>(qbuf,kbuf,vTbuf,biasb,xout);

  dim3 gp(NTOK/16, 5);
  gram_part<<<gp,256,0,stream>>>(xout,bRWTf,Gpart);
  route_xw<<<NTOK/16,256,0,stream>>>(Gpart,xout,xw);

  dim3 gf(NTOK/BM, DD/BN);
  final_gemm<<<gf,256,0,stream>>>(xw,bRWT,(float*)d_out);
}